// Round 1
// baseline (224.471 us; speedup 1.0000x reference)
//
#include <hip/hip_runtime.h>

// CapsuleBlock dynamic routing, MI355X.
// x: [64, 2048, 8] f32; W: [2048, 16, 8, 16] f32; out: [64, 16, 16] f32.
// R1 design: materialize hats (128MB in ws) + fused routing passes.
//   bias2 = hat.(out0+out1)  => no bias tensor ever materialized.
//   iter-0 softmax is uniform 1/16 => s0 folded into hats kernel.

#define B_    64
#define NIN   2048
#define DIN   8
#define NOUT  16
#define DOUT  16
#define NCHUNK 32   // n per block
#define NPW    8    // n per wave (NCHUNK / 4 waves)

// lane = k*4 + o4; lane covers hat[b,n,k,o4*4 .. o4*4+3] (one float4).
// Note: flat index k*16 + o4*4 == lane*4 exactly.
__device__ __forceinline__ float4 compute_hat(const float* __restrict__ x,
                                              const float* __restrict__ W,
                                              int b, int n, int k, int o4) {
    const float* xp = x + ((size_t)b * NIN + n) * DIN;
    float4 xa = *(const float4*)xp;          // x[d0..3], uniform across wave (broadcast)
    float4 xb = *(const float4*)(xp + 4);    // x[d4..7]
    const float* wp = W + ((size_t)n * NOUT + k) * (DIN * DOUT) + o4 * 4;
    float4 acc = make_float4(0.f, 0.f, 0.f, 0.f);
    float xs[8] = {xa.x, xa.y, xa.z, xa.w, xb.x, xb.y, xb.z, xb.w};
#pragma unroll
    for (int d = 0; d < 8; ++d) {
        float4 w = *(const float4*)(wp + d * DOUT);
        acc.x = fmaf(xs[d], w.x, acc.x);
        acc.y = fmaf(xs[d], w.y, acc.y);
        acc.z = fmaf(xs[d], w.z, acc.z);
        acc.w = fmaf(xs[d], w.w, acc.w);
    }
    return acc;
}

// Block-level reduce of per-thread float4 partials (256 threads -> 64 lanes)
// followed by scalar atomics into s[b*256 + lane*4 + j].
__device__ __forceinline__ void reduce_and_atomic(float4 acc, int b, float* __restrict__ s) {
    __shared__ float4 red[256];
    red[threadIdx.x] = acc;
    __syncthreads();
    if (threadIdx.x < 64) {
        float4 a = red[threadIdx.x];
        float4 c1 = red[threadIdx.x + 64];
        float4 c2 = red[threadIdx.x + 128];
        float4 c3 = red[threadIdx.x + 192];
        a.x += c1.x + c2.x + c3.x;
        a.y += c1.y + c2.y + c3.y;
        a.z += c1.z + c2.z + c3.z;
        a.w += c1.w + c2.w + c3.w;
        float* sp = s + b * 256 + threadIdx.x * 4;
        atomicAdd(sp + 0, a.x);
        atomicAdd(sp + 1, a.y);
        atomicAdd(sp + 2, a.z);
        atomicAdd(sp + 3, a.w);
    }
}

// K1: compute hats (optionally store) and accumulate s0_raw = sum_n hats.
__global__ __launch_bounds__(256) void k_hats_sum(const float* __restrict__ x,
                                                  const float* __restrict__ W,
                                                  float* __restrict__ hats,
                                                  float* __restrict__ s0) {
    int b = blockIdx.y;
    int nbase = blockIdx.x * NCHUNK;
    int lane = threadIdx.x & 63;
    int wave = threadIdx.x >> 6;
    int k = lane >> 2, o4 = lane & 3;
    float4 acc = make_float4(0.f, 0.f, 0.f, 0.f);
#pragma unroll
    for (int i = 0; i < NPW; ++i) {
        int n = nbase + wave * NPW + i;
        float4 h = compute_hat(x, W, b, n, k, o4);
        if (hats)
            *(float4*)&hats[(((size_t)b * NIN + n) << 8) + lane * 4] = h;
        acc.x += h.x; acc.y += h.y; acc.z += h.z; acc.w += h.w;
    }
    reduce_and_atomic(acc, b, s0);
}

// K3/K5: one routing pass. bias_k = hat . ov ; c = softmax_k(bias) ; s += c*hat.
__global__ __launch_bounds__(256) void k_route(const float* __restrict__ x,
                                               const float* __restrict__ W,
                                               const float* __restrict__ hats,
                                               const float* __restrict__ outP,
                                               const float* __restrict__ outQ,
                                               int useQ,
                                               float* __restrict__ sdst) {
    int b = blockIdx.y;
    int nbase = blockIdx.x * NCHUNK;
    int lane = threadIdx.x & 63;
    int wave = threadIdx.x >> 6;
    int k = lane >> 2, o4 = lane & 3;

    // per-lane output fragment (fixed for whole kernel): out[b, k, o4*4..+3]
    float4 ov = *(const float4*)&outP[b * 256 + lane * 4];
    if (useQ) {
        float4 q = *(const float4*)&outQ[b * 256 + lane * 4];
        ov.x += q.x; ov.y += q.y; ov.z += q.z; ov.w += q.w;
    }

    float4 acc = make_float4(0.f, 0.f, 0.f, 0.f);
#pragma unroll
    for (int i = 0; i < NPW; ++i) {
        int n = nbase + wave * NPW + i;
        float4 h;
        if (hats)
            h = *(const float4*)&hats[(((size_t)b * NIN + n) << 8) + lane * 4];
        else
            h = compute_hat(x, W, b, n, k, o4);

        // bias_k: dot over o (16). partial over this lane's 4 o's, then 4-lane group reduce.
        float part = h.x * ov.x + h.y * ov.y + h.z * ov.z + h.w * ov.w;
        part += __shfl_xor(part, 1);
        part += __shfl_xor(part, 2);   // now uniform within each 4-lane (same-k) group

        // softmax over k=16 groups: group values uniform -> masks 4,8,16,32 reduce across k.
        float m = part;
        m = fmaxf(m, __shfl_xor(m, 4));
        m = fmaxf(m, __shfl_xor(m, 8));
        m = fmaxf(m, __shfl_xor(m, 16));
        m = fmaxf(m, __shfl_xor(m, 32));
        float e = __expf(part - m);
        float es = e;
        es += __shfl_xor(es, 4);
        es += __shfl_xor(es, 8);
        es += __shfl_xor(es, 16);
        es += __shfl_xor(es, 32);
        float c = e / es;

        acc.x = fmaf(c, h.x, acc.x);
        acc.y = fmaf(c, h.y, acc.y);
        acc.z = fmaf(c, h.z, acc.z);
        acc.w = fmaf(c, h.w, acc.w);
    }
    reduce_and_atomic(acc, b, sdst);
}

// squash over o (last axis). t = k*16 + o. scale applied before squash
// (1/16 for iter-0 uniform softmax, 1 otherwise).
__global__ __launch_bounds__(256) void k_squash(const float* __restrict__ s,
                                                float scale,
                                                float* __restrict__ out) {
    int b = blockIdx.x;
    int t = threadIdx.x;
    float v = s[b * 256 + t] * scale;
    float sq = v * v;
    sq += __shfl_xor(sq, 1);
    sq += __shfl_xor(sq, 2);
    sq += __shfl_xor(sq, 4);
    sq += __shfl_xor(sq, 8);   // sum over 16-lane (same-k) group
    float sc = (sq / (1.f + sq)) * rsqrtf(sq);
    out[b * 256 + t] = v * sc;
}

extern "C" void kernel_launch(void* const* d_in, const int* in_sizes, int n_in,
                              void* d_out, int out_size, void* d_ws, size_t ws_size,
                              hipStream_t stream) {
    const float* x = (const float*)d_in[0];
    const float* W = (const float*)d_in[1];
    float* out = (float*)d_out;

    char* ws = (char*)d_ws;
    float* s0 = (float*)ws;                    // [64][256]
    float* s1 = s0 + B_ * 256;
    float* s2 = s1 + B_ * 256;
    float* out0 = s2 + B_ * 256;
    float* out1 = out0 + B_ * 256;
    size_t scalarBytes = (size_t)5 * B_ * 256 * sizeof(float);  // 320 KB
    size_t hatBytes = (size_t)B_ * NIN * 256 * sizeof(float);   // 128 MB
    float* hats = nullptr;
    if (ws_size >= scalarBytes + hatBytes)
        hats = (float*)(ws + scalarBytes);

    hipMemsetAsync(s0, 0, (size_t)3 * B_ * 256 * sizeof(float), stream);

    dim3 grid(NIN / NCHUNK, B_);
    k_hats_sum<<<grid, 256, 0, stream>>>(x, W, hats, s0);
    k_squash<<<B_, 256, 0, stream>>>(s0, 1.f / 16.f, out0);
    k_route<<<grid, 256, 0, stream>>>(x, W, hats, out0, out0, 0, s1);
    k_squash<<<B_, 256, 0, stream>>>(s1, 1.f, out1);
    k_route<<<grid, 256, 0, stream>>>(x, W, hats, out0, out1, 1, s2);
    k_squash<<<B_, 256, 0, stream>>>(s2, 1.f, out);
}